// Round 15
// baseline (832.365 us; speedup 1.0000x reference)
//
#include <hip/hip_runtime.h>
#include <hip/hip_bf16.h>

#define VOCAB 29
#define VEC   512
#define HID   1024
#define SEN   64
#define BATCH 2048

typedef __bf16 bf16_t;
typedef bf16_t bf16x8 __attribute__((ext_vector_type(8)));
typedef float  floatx4 __attribute__((ext_vector_type(4)));

// exact identity tanh(x) = 1 - 2/(exp(2x)+1); fp32 rounding error << bf16 ulp
__device__ __forceinline__ float fast_tanh(float x) {
    float e = __expf(2.0f * x);
    return 1.0f - 2.0f / (e + 1.0f);
}

// ============================================================================
// v16: v15's fusion (1 kernel: prologue cvt+proj, 63-step loop, classifier
// tail) with the K-LOOP RESTORED TO v8 VERBATIM. v15's regression (832 vs
// 652) was self-inflicted: the inlined ring had 4-chunk (~280cyc) lookahead
// vs v8's 4-group/8-chunk (~560cyc) -> exposed post-inv L2 latency per chunk
// (the v6/v11 failure mode, third sighting). Also pv reads from Psh had a
// 4-way bank alias (row stride 256B == 0 mod 32 banks): Psh padded to [29][65].
//   - prologue: W_hh fp32 -> bf16 swizzled straight into Bsh (ds_write needs
//     no DMA lane-linearity); proj slice into Psh (same fp32 dot order).
//   - loop: v8's afb[4][2] ring, group=2 chunks, refill i+4, tk at i==12,
//     panel sync fast/safe + early buffer_inv. Numerics identical.
//   - tail: by==0 blocks compute the classifier panel (A = L2-hot h, B
//     cvt'd from fp32 W_cls in the same chunk order as the proven R2 kernel).
// ============================================================================
#define BM 128
#define BN 64
#define PANEL_BLKS 16
#define SB() __builtin_amdgcn_sched_barrier(0)

// load A fragments for K-group G (chunks 2G,2G+1): tile 16x64 -> 1 frag/chunk
#define LOAD_G(B, G) {                                               \
    const int c0_ = 2 * (G);                                         \
    afb[B][0] = *(const bf16x8*)(hA + c0_ * 32);                     \
    afb[B][1] = *(const bf16x8*)(hA + (c0_ + 1) * 32); }

// compute K-group G from ring slot B: 2 chunks x {4 ds_read_b128, 4 MFMA}
#define COMP_G(B, G)                                                 \
    _Pragma("unroll")                                                \
    for (int j = 0; j < 2; j++) {                                    \
        const int c_ = 2 * (G) + j;                                  \
        const int pq = ((4 * c_ + q) ^ l7) * 8;                      \
        bf16x8 b0 = *(const bf16x8*)&Bsh[l16][pq];                   \
        bf16x8 b1 = *(const bf16x8*)&Bsh[16 + l16][pq];              \
        bf16x8 b2 = *(const bf16x8*)&Bsh[32 + l16][pq];              \
        bf16x8 b3 = *(const bf16x8*)&Bsh[48 + l16][pq];              \
        bf16x8 a0 = afb[B][j];                                       \
        acc[0] = __builtin_amdgcn_mfma_f32_16x16x32_bf16(a0, b0, acc[0], 0, 0, 0); \
        acc[1] = __builtin_amdgcn_mfma_f32_16x16x32_bf16(a0, b1, acc[1], 0, 0, 0); \
        acc[2] = __builtin_amdgcn_mfma_f32_16x16x32_bf16(a0, b2, acc[2], 0, 0, 0); \
        acc[3] = __builtin_amdgcn_mfma_f32_16x16x32_bf16(a0, b3, acc[3], 0, 0, 0); \
    }

__global__ __launch_bounds__(512, 2)
void rnn_all(const float* __restrict__ whh32, const float* __restrict__ emb,
             const float* __restrict__ wih, const float* __restrict__ wcls32,
             const float* __restrict__ bcls, const int* __restrict__ x,
             bf16_t* hbuf, float* out, int* scnt)
{
    __shared__ __align__(16) bf16_t Bsh[BN][HID];       // 128 KB, swizzled chunks
    __shared__ __align__(16) float  Psh[VOCAB][BN + 1]; // pad: stride 65 words kills
    __shared__ int uni_sh;                              //      the 4-way tok alias

    const int tid  = threadIdx.x;
    const int bx   = blockIdx.x, by = blockIdx.y;
    const int m0   = bx * BM;
    const int n0   = by * BN;
    const int wave = tid >> 6;         // 8 waves
    const int lane = tid & 63;
    const int wm   = wave * 16;        // wave tile 16 x 64 (m-split 8 ways)
    const int q    = lane >> 4;
    const int l16  = lane & 15;
    const int l7   = l16 & 7;

    int* cnt   = scnt + bx * 64;            // per-panel counter (256B stride)
    int* xmask = scnt + (16 + bx) * 64;     // per-panel XCD mask

    // ---- prologue 1: W_hh fp32 slice -> bf16, swizzled, straight into LDS.
    //      Slot (r,j) holds global chunk j^(r&7) (the layout the loop reads).
#pragma unroll
    for (int k = 0; k < 16; k++) {
        const int idx = tid + k * 512;          // 8192 16B-slots
        const int r = idx >> 7, j = idx & 127;
        const float* src = whh32 + (size_t)(n0 + r) * HID + (j ^ (r & 7)) * 8;
        float4 a = *(const float4*)src;
        float4 b = *(const float4*)(src + 4);
        bf16x8 v;
        v[0] = (bf16_t)a.x; v[1] = (bf16_t)a.y; v[2] = (bf16_t)a.z; v[3] = (bf16_t)a.w;
        v[4] = (bf16_t)b.x; v[5] = (bf16_t)b.y; v[6] = (bf16_t)b.z; v[7] = (bf16_t)b.w;
        *(bf16x8*)&Bsh[r][j * 8] = v;
    }

    // ---- prologue 2: proj slice Psh[v][col] = dot(emb[v], W_ih[n0+col])
    //      (exact same accumulation order as the old proj_kernel)
    for (int p = tid; p < VOCAB * BN; p += 512) {
        const int v = p / BN, col = p % BN;
        const float* e = emb + v * VEC;
        const float* w = wih + (n0 + col) * VEC;
        float s = 0.f;
        for (int kk = 0; kk < VEC; kk += 4) {
            float4 ev = *(const float4*)(e + kk);
            float4 wv = *(const float4*)(w + kk);
            s += ev.x * wv.x + ev.y * wv.y + ev.z * wv.z + ev.w * wv.w;
        }
        Psh[v][col] = s;
    }
    __syncthreads();   // Bsh + Psh ready

    // rows this lane owns (C/D row = q*4+reg, col = l16)
    int rowl[4];
#pragma unroll
    for (int r = 0; r < 4; r++) rowl[r] = m0 + wm + q * 4 + r;

    // ---- t = 0: h = tanh(proj[x[:,0]]) (h_prev = 0)
#pragma unroll
    for (int i = 0; i < 4; i++) {
        const int tok = x[rowl[i] * SEN + 0];
#pragma unroll
        for (int ni = 0; ni < 4; ni++) {
            const float v = Psh[tok][ni * 16 + l16];
            hbuf[rowl[i] * HID + n0 + ni * 16 + l16] = (bf16_t)fast_tanh(v);
        }
    }

    // tokens for t=1 (prefetched)
    int tk[4];
#pragma unroll
    for (int i = 0; i < 4; i++) tk[i] = x[rowl[i] * SEN + 1];

    // ---- first sync: ALWAYS full release/acquire; publishes XCD mask
    __syncthreads();   // drains t0 stores
    if (tid == 0) {
        const int my_xcd = (int)__builtin_amdgcn_s_getreg((3 << 11) | 20);  // HW_REG_XCC_ID
        __hip_atomic_fetch_or(xmask, 1 << my_xcd, __ATOMIC_RELAXED, __HIP_MEMORY_SCOPE_AGENT);
        __hip_atomic_fetch_add(cnt, 1, __ATOMIC_RELEASE, __HIP_MEMORY_SCOPE_AGENT);
        while (__hip_atomic_load(cnt, __ATOMIC_ACQUIRE, __HIP_MEMORY_SCOPE_AGENT) < PANEL_BLKS)
            __builtin_amdgcn_s_sleep(1);
        const int m = __hip_atomic_load(xmask, __ATOMIC_RELAXED, __HIP_MEMORY_SCOPE_AGENT);
        uni_sh = ((m & (m - 1)) == 0);   // one XCD bit -> same-L2 fast path legal
    }
    __syncthreads();
    asm volatile("buffer_inv" ::: "memory");
    const int fast = uni_sh;

    // ======================= v8 K-loop, verbatim ===========================
#pragma unroll 1
    for (int t = 1; t < SEN; t++) {
        const bf16_t* h_in  = hbuf + (size_t)((t + 1) & 1) * (BATCH * HID);
        bf16_t*       h_out = hbuf + (size_t)(t & 1) * (BATCH * HID);

        floatx4 acc[4];
#pragma unroll
        for (int j = 0; j < 4; j++) acc[j] = (floatx4){0.f, 0.f, 0.f, 0.f};

        // A-fragment base: lane (q,l16) holds h_in[wm+l16][c*32 + q*8 .. +7]
        const bf16_t* hA = h_in + (size_t)(m0 + wm + l16) * HID + q * 8;
        bf16x8 afb[4][2];   // 4-group ring, 8-chunk (~560cyc) lookahead

        // prologue: prefetch groups 0..3 (chunks 0..7 in flight)
        LOAD_G(0, 0) LOAD_G(1, 1) LOAD_G(2, 2) LOAD_G(3, 3)

        // proj rows for THIS step (tk prefetched last step) — LDS, padded
        float pv[4][4];
#pragma unroll
        for (int i = 0; i < 4; i++)
#pragma unroll
            for (int ni = 0; ni < 4; ni++)
                pv[i][ni] = Psh[tk[i]][ni * 16 + l16];
        SB();

        // ---- main ring: compute group i, refill slot with group i+4 --------
#pragma unroll
        for (int i = 0; i < 16; i++) {
            COMP_G(i & 3, i)
            if (i < 12) { LOAD_G(i & 3, i + 4) }
            if (i == 12 && t < SEN - 1) {   // tokens for t+1, off critical path
#pragma unroll
                for (int ii = 0; ii < 4; ii++) tk[ii] = x[rowl[ii] * SEN + t + 1];
            }
            SB();   // loads issued before next group's compute region
        }

        // epilogue: + proj, tanh, store
#pragma unroll
        for (int r = 0; r < 4; r++)
#pragma unroll
            for (int ni = 0; ni < 4; ni++) {
                float v = acc[ni][r] + pv[r][ni];
                h_out[rowl[r] * HID + n0 + ni * 16 + l16] = (bf16_t)fast_tanh(v);
            }

        // ---- panel sync (t=63 handled by the final sync below) ------------
        if (t < SEN - 1) {
            __syncthreads();   // vmcnt(0): this block's h stores are in L2
            asm volatile("buffer_inv" ::: "memory");   // early-inv (v13-proven)
            if (fast) {        // same-L2: relaxed counter, no cache maintenance
                if (tid == 0) {
                    __hip_atomic_fetch_add(cnt, 1, __ATOMIC_RELAXED, __HIP_MEMORY_SCOPE_AGENT);
                    while (__hip_atomic_load(cnt, __ATOMIC_RELAXED, __HIP_MEMORY_SCOPE_AGENT)
                           < PANEL_BLKS * (t + 1))
                        __builtin_amdgcn_s_sleep(1);
                }
            } else {           // cross-XCD fallback: full release/acquire
                if (tid == 0) {
                    __hip_atomic_fetch_add(cnt, 1, __ATOMIC_RELEASE, __HIP_MEMORY_SCOPE_AGENT);
                    while (__hip_atomic_load(cnt, __ATOMIC_ACQUIRE, __HIP_MEMORY_SCOPE_AGENT)
                           < PANEL_BLKS * (t + 1))
                        __builtin_amdgcn_s_sleep(1);
                }
            }
            __syncthreads();
        }
    }

    // ================== fused classifier tail ==============================
    // final sync: make every panel's t=63 columns L2-visible
    __syncthreads();   // drain t=63 stores
    if (tid == 0) {
        if (fast)
            __hip_atomic_fetch_add(cnt, 1, __ATOMIC_RELAXED, __HIP_MEMORY_SCOPE_AGENT);
        else
            __hip_atomic_fetch_add(cnt, 1, __ATOMIC_RELEASE, __HIP_MEMORY_SCOPE_AGENT);
    }
    if (by != 0) return;   // 15/16 blocks done; one block per panel finishes

    if (tid == 0) {
        if (fast) {
            while (__hip_atomic_load(cnt, __ATOMIC_RELAXED, __HIP_MEMORY_SCOPE_AGENT)
                   < PANEL_BLKS * SEN)
                __builtin_amdgcn_s_sleep(1);
        } else {
            while (__hip_atomic_load(cnt, __ATOMIC_ACQUIRE, __HIP_MEMORY_SCOPE_AGENT)
                   < PANEL_BLKS * SEN)
                __builtin_amdgcn_s_sleep(1);
        }
    }
    __syncthreads();
    asm volatile("buffer_inv" ::: "memory");   // L1 refetch -> fresh L2 h

    // out[m0+wm .. +15][0..64] per wave; A from h (L2), B cvt'd from fp32 W_cls.
    // Same chunk order (c = 0..31) as the proven R2 classifier -> same sums.
    {
        const bf16_t* h1 = hbuf + (size_t)((SEN - 1) & 1) * (BATCH * HID);
        const bf16_t* hA = h1 + (size_t)(m0 + wm + l16) * HID + q * 8;

        floatx4 acc[5];
#pragma unroll
        for (int j = 0; j < 5; j++) acc[j] = (floatx4){0.f, 0.f, 0.f, 0.f};

#pragma unroll 1
        for (int c = 0; c < 32; c++) {
            bf16x8 af = *(const bf16x8*)(hA + c * 32);
            bf16x8 bfr[5];
#pragma unroll
            for (int ni = 0; ni < 5; ni++) {
                const int gn = ni * 16 + l16;
                bf16x8 v;
                if (gn < SEN + 1) {
                    const float* src = wcls32 + (size_t)gn * HID + c * 32 + q * 8;
                    float4 a = *(const float4*)src;
                    float4 b = *(const float4*)(src + 4);
                    v[0] = (bf16_t)a.x; v[1] = (bf16_t)a.y; v[2] = (bf16_t)a.z; v[3] = (bf16_t)a.w;
                    v[4] = (bf16_t)b.x; v[5] = (bf16_t)b.y; v[6] = (bf16_t)b.z; v[7] = (bf16_t)b.w;
                } else {
                    v = (bf16x8){(bf16_t)0.f, (bf16_t)0.f, (bf16_t)0.f, (bf16_t)0.f,
                                 (bf16_t)0.f, (bf16_t)0.f, (bf16_t)0.f, (bf16_t)0.f};
                }
                bfr[ni] = v;
            }
#pragma unroll
            for (int ni = 0; ni < 5; ni++)
                acc[ni] = __builtin_amdgcn_mfma_f32_16x16x32_bf16(af, bfr[ni], acc[ni], 0, 0, 0);
        }

#pragma unroll
        for (int r = 0; r < 4; r++) {
            const int gm = m0 + wm + q * 4 + r;
#pragma unroll
            for (int ni = 0; ni < 5; ni++) {
                const int gn = ni * 16 + l16;
                if (gn < SEN + 1)
                    out[gm * (SEN + 1) + gn] = acc[ni][r] + bcls[gn];
            }
        }
    }
}

#undef LOAD_G
#undef COMP_G

extern "C" void kernel_launch(void* const* d_in, const int* in_sizes, int n_in,
                              void* d_out, int out_size, void* d_ws, size_t ws_size,
                              hipStream_t stream)
{
    const int*   x     = (const int*)  d_in[0];
    const float* emb   = (const float*)d_in[1];
    const float* w_ih  = (const float*)d_in[2];
    const float* w_hh  = (const float*)d_in[3];
    const float* w_cls = (const float*)d_in[4];
    const float* b_cls = (const float*)d_in[5];
    float* out = (float*)d_out;

    char* ws = (char*)d_ws;
    bf16_t* h0   = (bf16_t*)ws;                   // 4 MB (t even); h1 at +4MB (t odd)
    int*    scnt = (int*)(ws + (8u << 20));       // sync area

    hipMemsetAsync(scnt, 0, 16384, stream);

    dim3 grid(BATCH / BM, HID / BN);   // (16,16) = 256 blocks = 1/CU (~136 KB LDS)
    rnn_all<<<grid, 512, 0, stream>>>(w_hh, emb, w_ih, w_cls, b_cls, x, h0, out, scnt);
}